// Round 2
// baseline (533.200 us; speedup 1.0000x reference)
//
#include <hip/hip_runtime.h>

// LSTM: B=4096 sequences, T=2048 steps, H=4, input dim 1, + linear head to 1.
// Strategy: one QUAD of lanes per *pair* of sequences (k=2 interleaving).
// Lane j owns h[j], c[j] and gate rows {j, 4+j, 8+j, 12+j} for BOTH of its
// quad's sequences (seqs 2q and 2q+1). The two chains are independent, so the
// SIMD fills chain-latency bubbles of chain A with instructions of chain B.
// Cross-lane traffic (h broadcast, y reduce) stays intra-quad via DPP.
// Activation scales (log2 e) are pre-folded into weights; cell state is kept
// pre-scaled by 2*log2e so tanh(c) needs no multiply on the chain.

#define L2E 1.44269504088896340736f

constexpr int TLEN = 2048;

template <int CTRL>
__device__ __forceinline__ float qperm(float v) {
    return __int_as_float(
        __builtin_amdgcn_mov_dpp(__float_as_int(v), CTRL, 0xF, 0xF, true));
}

__device__ __forceinline__ float fexp2(float x) { return __builtin_amdgcn_exp2f(x); }
__device__ __forceinline__ float frcp(float x) { return __builtin_amdgcn_rcpf(x); }

__global__ __launch_bounds__(64) void lstm4_kernel(
    const float* __restrict__ x,      // [B, T]
    const float* __restrict__ W_ih,   // [16, 1]
    const float* __restrict__ W_hh,   // [16, 4]
    const float* __restrict__ b_ih,   // [16]
    const float* __restrict__ b_hh,   // [16]
    const float* __restrict__ W_lin,  // [1, 4]
    const float* __restrict__ b_lin,  // [1]
    float* __restrict__ out)          // [B, T]
{
    const int tid  = blockIdx.x * 64 + threadIdx.x;
    const int quad = tid >> 2;       // global quad index, [0, 2048)
    const int j    = tid & 3;

    // Gate rows for this lane's column j (PyTorch order i,f,g,o).
    const int ri = j, rf = 4 + j, rg = 8 + j, ro = 12 + j;
    // sigmoid(z) = 1/(1+exp2(-z*L2E))   -> scale i,f,o rows by -L2E
    // tanh(z)    = 1-2/(1+exp2(2z*L2E)) -> scale g row by +2*L2E
    const float si = -L2E, sf = -L2E, sg = 2.0f * L2E, so = -L2E;

    const float wih_i = W_ih[ri] * si;
    const float wih_f = W_ih[rf] * sf;
    const float wih_g = W_ih[rg] * sg;
    const float wih_o = W_ih[ro] * so;

    const float bi = (b_ih[ri] + b_hh[ri]) * si;
    const float bf = (b_ih[rf] + b_hh[rf]) * sf;
    const float bg = (b_ih[rg] + b_hh[rg]) * sg;
    const float bo = (b_ih[ro] + b_hh[ro]) * so;

    const float wi0 = W_hh[ri * 4 + 0] * si, wi1 = W_hh[ri * 4 + 1] * si,
                wi2 = W_hh[ri * 4 + 2] * si, wi3 = W_hh[ri * 4 + 3] * si;
    const float wf0 = W_hh[rf * 4 + 0] * sf, wf1 = W_hh[rf * 4 + 1] * sf,
                wf2 = W_hh[rf * 4 + 2] * sf, wf3 = W_hh[rf * 4 + 3] * sf;
    const float wg0 = W_hh[rg * 4 + 0] * sg, wg1 = W_hh[rg * 4 + 1] * sg,
                wg2 = W_hh[rg * 4 + 2] * sg, wg3 = W_hh[rg * 4 + 3] * sg;
    const float wo0 = W_hh[ro * 4 + 0] * so, wo1 = W_hh[ro * 4 + 1] * so,
                wo2 = W_hh[ro * 4 + 2] * so, wo3 = W_hh[ro * 4 + 3] * so;

    const float wlin = W_lin[j];
    const float blin = b_lin[0];

    const float* xpA = x + (size_t)(2 * quad) * TLEN;
    const float* xpB = xpA + TLEN;
    float*       opA = out + (size_t)(2 * quad) * TLEN;
    float*       opB = opA + TLEN;

    float hA = 0.0f, CA = 0.0f;   // C is c pre-scaled by 2*L2E
    float hB = 0.0f, CB = 0.0f;

    // One LSTM step for one chain. C is the 2*L2E-scaled cell state.
    auto step = [&](float xs, float& h, float& C) -> float {
        const float h0 = qperm<0x00>(h);
        const float h1 = qperm<0x55>(h);
        const float h2 = qperm<0xAA>(h);
        const float h3 = qperm<0xFF>(h);

        float gi = fmaf(xs, wih_i, bi);
        gi = fmaf(wi0, h0, gi); gi = fmaf(wi1, h1, gi);
        gi = fmaf(wi2, h2, gi); gi = fmaf(wi3, h3, gi);

        float gf = fmaf(xs, wih_f, bf);
        gf = fmaf(wf0, h0, gf); gf = fmaf(wf1, h1, gf);
        gf = fmaf(wf2, h2, gf); gf = fmaf(wf3, h3, gf);

        float gg = fmaf(xs, wih_g, bg);
        gg = fmaf(wg0, h0, gg); gg = fmaf(wg1, h1, gg);
        gg = fmaf(wg2, h2, gg); gg = fmaf(wg3, h3, gg);

        float go = fmaf(xs, wih_o, bo);
        go = fmaf(wo0, h0, go); go = fmaf(wo1, h1, go);
        go = fmaf(wo2, h2, go); go = fmaf(wo3, h3, go);

        const float ii = frcp(1.0f + fexp2(gi));
        const float ff = frcp(1.0f + fexp2(gf));
        const float oo = frcp(1.0f + fexp2(go));
        // tg2 = 2*L2E * tanh-part: fma(-4*L2E, r, 2*L2E)
        const float rg_ = frcp(1.0f + fexp2(gg));
        const float tg2 = fmaf(-4.0f * L2E, rg_, 2.0f * L2E);

        C = fmaf(ff, C, ii * tg2);                    // scaled cell update
        const float tc = fmaf(-2.0f, frcp(1.0f + fexp2(C)), 1.0f);
        h = oo * tc;

        float p = wlin * h;
        p += qperm<0xB1>(p);  // [1,0,3,2]
        p += qperm<0x4E>(p);  // [2,3,0,1]
        return p + blin;
    };

    // Software-pipelined x stream: 8 steps (2x float4) per chain per group,
    // prefetched one group ahead.
    float4 xaA = *(const float4*)(xpA);
    float4 xbA = *(const float4*)(xpA + 4);
    float4 xaB = *(const float4*)(xpB);
    float4 xbB = *(const float4*)(xpB + 4);

    for (int t = 0; t < TLEN; t += 8) {
        int tn = t + 8;
        if (tn > TLEN - 8) tn = 0;  // safe dummy address for last group
        const float4 xaA_n = *(const float4*)(xpA + tn);
        const float4 xbA_n = *(const float4*)(xpA + tn + 4);
        const float4 xaB_n = *(const float4*)(xpB + tn);
        const float4 xbB_n = *(const float4*)(xpB + tn + 4);

        const float xsA[8] = {xaA.x, xaA.y, xaA.z, xaA.w, xbA.x, xbA.y, xbA.z, xbA.w};
        const float xsB[8] = {xaB.x, xaB.y, xaB.z, xaB.w, xbB.x, xbB.y, xbB.z, xbB.w};
        float yA[8], yB[8];

#pragma unroll
        for (int u = 0; u < 8; ++u) {
            yA[u] = step(xsA[u], hA, CA);
            yB[u] = step(xsB[u], hB, CB);
        }

        if (j == 0) {
            *(float4*)(opA + t)     = make_float4(yA[0], yA[1], yA[2], yA[3]);
            *(float4*)(opA + t + 4) = make_float4(yA[4], yA[5], yA[6], yA[7]);
            *(float4*)(opB + t)     = make_float4(yB[0], yB[1], yB[2], yB[3]);
            *(float4*)(opB + t + 4) = make_float4(yB[4], yB[5], yB[6], yB[7]);
        }

        xaA = xaA_n; xbA = xbA_n;
        xaB = xaB_n; xbB = xbB_n;
    }
}

extern "C" void kernel_launch(void* const* d_in, const int* in_sizes, int n_in,
                              void* d_out, int out_size, void* d_ws, size_t ws_size,
                              hipStream_t stream) {
    const float* x     = (const float*)d_in[0];
    const float* W_ih  = (const float*)d_in[1];
    const float* W_hh  = (const float*)d_in[2];
    const float* b_ih  = (const float*)d_in[3];
    const float* b_hh  = (const float*)d_in[4];
    const float* W_lin = (const float*)d_in[5];
    const float* b_lin = (const float*)d_in[6];
    float* out = (float*)d_out;

    const int B = in_sizes[0] / TLEN;        // 4096
    const int threads = (B / 2) * 4;         // quad per sequence-PAIR (k=2)
    const int block = 64;                    // 1 wave per block
    const int grid = threads / block;        // 128 blocks -> 128 CUs

    lstm4_kernel<<<grid, block, 0, stream>>>(x, W_ih, W_hh, b_ih, b_hh,
                                             W_lin, b_lin, out);
}

// Round 3
// 309.803 us; speedup vs baseline: 1.7211x; 1.7211x over previous
//
#include <hip/hip_runtime.h>

// LSTM B=4096, T=2048, H=4 + linear head. 16 lanes per sequence: lane r
// (0..15) owns gate row r (i:0-3, f:4-7, g:8-11, o:12-15), column j0 = r&3.
// Rationale: single-wave issue cadence (~4-5 cyc/instr) is the limiter, so
// minimize instrs/step/wave and maximize wave count: 1024 waves (1/SIMD
// chip-wide), ~31 instrs/step vs round-1's 256 waves / ~55 instrs.
// Cross-lane: 3 quad_perm (h partners, per-lane-reordered weights),
// 3 row_shl (gather f/g/o to column lanes), 1 ds_swizzle (replicate h to all
// quads of the row). Activations branch-free via per-lane affine (Aact,Bact);
// cell state kept pre-scaled by 2*log2e so tanh(c) needs no extra multiply.

#define L2E 1.44269504088896340736f

constexpr int TLEN = 2048;

template <int CTRL>
__device__ __forceinline__ float qperm(float v) {
    return __int_as_float(
        __builtin_amdgcn_mov_dpp(__float_as_int(v), CTRL, 0xF, 0xF, true));
}
// row_shl:N — lane i reads lane i+N within its 16-lane row (0 if OOB).
template <int N>
__device__ __forceinline__ float rowshl(float v) {
    return __int_as_float(
        __builtin_amdgcn_mov_dpp(__float_as_int(v), 0x100 + N, 0xF, 0xF, true));
}
// ds_swizzle bit-mode, and_mask=0x13: src = lane & 0x13 — replicates lanes
// {0..3} / {16..19} of each 32-lane group across their 16-lane rows.
__device__ __forceinline__ float swz13(float v) {
    return __int_as_float(__builtin_amdgcn_ds_swizzle(__float_as_int(v), 0x0013));
}

__device__ __forceinline__ float fexp2(float x) { return __builtin_amdgcn_exp2f(x); }
__device__ __forceinline__ float frcp(float x)  { return __builtin_amdgcn_rcpf(x); }

__global__ __launch_bounds__(256) void lstm16_kernel(
    const float* __restrict__ x,      // [B, T]
    const float* __restrict__ W_ih,   // [16]
    const float* __restrict__ W_hh,   // [16, 4]
    const float* __restrict__ b_ih,   // [16]
    const float* __restrict__ b_hh,   // [16]
    const float* __restrict__ W_lin,  // [4]
    const float* __restrict__ b_lin,  // [1]
    float* __restrict__ out)          // [B, T]
{
    const int tid  = blockIdx.x * 256 + threadIdx.x;
    const int seq  = tid >> 4;        // one 16-lane row per sequence
    const int r    = tid & 15;        // gate row
    const int j0   = r & 3;           // column this lane's row feeds
    const int gate = r >> 2;          // 0=i 1=f 2=g 3=o

    // sigmoid(z) = 1/(1+exp2(-z*L2E))   -> scale i,f,o rows by -L2E
    // tanh(z)    = 1-2/(1+exp2(2z*L2E)) -> scale g row by +2*L2E
    const float s = (gate == 2) ? (2.0f * L2E) : (-L2E);

    const float wih  = W_ih[r] * s;
    const float bias = (b_ih[r] + b_hh[r]) * s;
    // Per-lane reordered recurrent weights: own-h first, then quad_perm
    // partners j0^1, j0^2, j0^3.
    const float wh_s = W_hh[r * 4 + j0] * s;
    const float wh_a = W_hh[r * 4 + (j0 ^ 1)] * s;
    const float wh_b = W_hh[r * 4 + (j0 ^ 2)] * s;
    const float wh_c = W_hh[r * 4 + (j0 ^ 3)] * s;
    // Uniform activation map: v = Aact*r + Bact.
    //   sigmoid rows: v = r.   g rows: v = 2*L2E*tanh = -4*L2E*r + 2*L2E.
    const float Aact = (gate == 2) ? (-4.0f * L2E) : 1.0f;
    const float Bact = (gate == 2) ? ( 2.0f * L2E) : 0.0f;

    const float wlin = W_lin[j0];
    const float blin = b_lin[0];

    const float* xp = x + (size_t)seq * TLEN;
    float*       op = out + (size_t)seq * TLEN;

    float h = 0.0f;   // h_{lane&3}, replicated into every quad of the row
    float C = 0.0f;   // 2*L2E-scaled cell state; valid on lanes 0-3 only

    // x stream: 8 steps (2x float4) per group, prefetched one group ahead.
    float4 xa = *(const float4*)(xp);
    float4 xb = *(const float4*)(xp + 4);

    for (int t = 0; t < TLEN; t += 8) {
        int tn = t + 8;
        if (tn > TLEN - 8) tn = 0;  // safe dummy address for last group
        const float4 xa_n = *(const float4*)(xp + tn);
        const float4 xb_n = *(const float4*)(xp + tn + 4);

        const float xs[8] = {xa.x, xa.y, xa.z, xa.w, xb.x, xb.y, xb.z, xb.w};
        float y[8];

#pragma unroll
        for (int u = 0; u < 8; ++u) {
            // Quad partners of the replicated h.
            const float ha = qperm<0xB1>(h);   // h_{j0^1}
            const float hb = qperm<0x4E>(h);   // h_{j0^2}
            const float hc = qperm<0x1B>(h);   // h_{j0^3}

            // This lane's single gate pre-activation (scale pre-folded).
            float z = fmaf(xs[u], wih, bias);
            z = fmaf(wh_s, h,  z);
            z = fmaf(wh_a, ha, z);
            z = fmaf(wh_b, hb, z);
            z = fmaf(wh_c, hc, z);

            const float rr = frcp(1.0f + fexp2(z));
            const float v  = fmaf(Aact, rr, Bact);  // i/f/o: sigmoid; g: 2L2E*tanh

            // Gather f, g, o values onto the column lanes (0-3).
            const float fv = rowshl<4>(v);    // f_j
            const float gv = rowshl<8>(v);    // 2L2E*tanh(g_j)
            const float ov = rowshl<12>(v);   // o_j

            // Lanes 0-3: v == i_j. (Lanes 4-15 compute garbage, discarded.)
            C = fmaf(fv, C, v * gv);          // scaled cell update
            const float tc = fmaf(-2.0f, frcp(1.0f + fexp2(C)), 1.0f);
            const float hn = ov * tc;

            // Replicate h0..h3 (lanes 0-3) into all quads of the row.
            h = swz13(hn);

            // y_t = sum_j wlin_j h_j + blin via intra-quad butterfly.
            float p = wlin * h;
            p += qperm<0xB1>(p);
            p += qperm<0x4E>(p);
            y[u] = p + blin;
        }

        if (r == 0) {
            *(float4*)(op + t)     = make_float4(y[0], y[1], y[2], y[3]);
            *(float4*)(op + t + 4) = make_float4(y[4], y[5], y[6], y[7]);
        }

        xa = xa_n;
        xb = xb_n;
    }
}

extern "C" void kernel_launch(void* const* d_in, const int* in_sizes, int n_in,
                              void* d_out, int out_size, void* d_ws, size_t ws_size,
                              hipStream_t stream) {
    const float* x     = (const float*)d_in[0];
    const float* W_ih  = (const float*)d_in[1];
    const float* W_hh  = (const float*)d_in[2];
    const float* b_ih  = (const float*)d_in[3];
    const float* b_hh  = (const float*)d_in[4];
    const float* W_lin = (const float*)d_in[5];
    const float* b_lin = (const float*)d_in[6];
    float* out = (float*)d_out;

    const int B = in_sizes[0] / TLEN;          // 4096
    const int threads = B * 16;                // 16 lanes per sequence
    const int block = 256;                     // 4 waves/block -> 1 block/CU
    const int grid = threads / block;          // 256 blocks, 1024 waves total

    lstm16_kernel<<<grid, block, 0, stream>>>(x, W_ih, W_hh, b_ih, b_hh,
                                              W_lin, b_lin, out);
}

// Round 4
// 265.174 us; speedup vs baseline: 2.0108x; 1.1683x over previous
//
#include <hip/hip_runtime.h>

// LSTM B=4096, T=2048, H=4 + linear head. TRANSPOSED 16-lane layout:
// lane r owns gate g0 = r&3 (i,f,g,o) of column jc = r>>2. All four gates of
// a column live in one QUAD -> post-activation gather is quad_perm (VALU DPP),
// and C/h are computed redundantly on all lanes (quad-uniform), so there is
// NO ds_swizzle anywhere: the whole recurrence chain stays on the VALU pipe.
// (Round-3 post-mortem: the per-step ds_swizzle's DS-pipe latency (~100+ cyc)
// was the limiter, not issue rate.)
// Cross-quad h gather uses direction-unambiguous DPP only:
//   row_half_mirror -> h_{jc^1}, row_ror:8 -> h_{jc^2}, row_mirror -> h_{jc^3}
// (h is quad-uniform, so within-quad lane reversal by the mirrors is harmless).
// Activation scales (log2 e) pre-folded into weights; cell state kept
// pre-scaled by 2*log2e so tanh(c) needs no multiply on the chain.

#define L2E 1.44269504088896340736f

constexpr int TLEN = 2048;

template <int CTRL>
__device__ __forceinline__ float dpp(float v) {
    return __int_as_float(
        __builtin_amdgcn_mov_dpp(__float_as_int(v), CTRL, 0xF, 0xF, true));
}
__device__ __forceinline__ float fexp2(float x) { return __builtin_amdgcn_exp2f(x); }
__device__ __forceinline__ float frcp(float x)  { return __builtin_amdgcn_rcpf(x); }

__global__ __launch_bounds__(256) void lstm16t_kernel(
    const float* __restrict__ x,      // [B, T]
    const float* __restrict__ W_ih,   // [16]
    const float* __restrict__ W_hh,   // [16, 4]
    const float* __restrict__ b_ih,   // [16]
    const float* __restrict__ b_hh,   // [16]
    const float* __restrict__ W_lin,  // [4]
    const float* __restrict__ b_lin,  // [1]
    float* __restrict__ out)          // [B, T]
{
    const int tid = blockIdx.x * 256 + threadIdx.x;
    const int seq = tid >> 4;         // one 16-lane row per sequence
    const int r   = tid & 15;
    const int g0  = r & 3;            // gate owned: 0=i 1=f 2=g 3=o
    const int jc  = r >> 2;           // hidden column owned by this quad
    const int row = g0 * 4 + jc;      // row in the [16,*] weight blocks

    // sigmoid(z) = 1/(1+exp2(-z*L2E))   -> scale i,f,o rows by -L2E
    // tanh(z)    = 1-2/(1+exp2(2z*L2E)) -> scale g row by +2*L2E
    const float s = (g0 == 2) ? (2.0f * L2E) : (-L2E);

    const float wih  = W_ih[row] * s;
    const float bias = (b_ih[row] + b_hh[row]) * s;
    // Weights paired with the direction-free DPP gathers below.
    const float wh_0 = W_hh[row * 4 + jc]       * s;
    const float wh_1 = W_hh[row * 4 + (jc ^ 1)] * s;
    const float wh_2 = W_hh[row * 4 + (jc ^ 2)] * s;
    const float wh_3 = W_hh[row * 4 + (jc ^ 3)] * s;
    // v = Aact * rcp(1+exp2(z)) + Bact: i/f/o -> sigmoid; g -> 2*L2E*tanh.
    const float Aact = (g0 == 2) ? (-4.0f * L2E) : 1.0f;
    const float Bact = (g0 == 2) ? ( 2.0f * L2E) : 0.0f;

    const float wlin = W_lin[jc];
    const float blin = b_lin[0];

    const float* xp = x + (size_t)seq * TLEN;
    float*       op = out + (size_t)seq * TLEN;

    float h = 0.0f;   // h_jc, quad-uniform (all lanes of the quad identical)
    float C = 0.0f;   // 2*L2E-scaled cell state, quad-uniform

    // x stream: 8 steps (2x float4) per group, prefetched one group ahead.
    float4 xa = *(const float4*)(xp);
    float4 xb = *(const float4*)(xp + 4);

    for (int t = 0; t < TLEN; t += 8) {
        int tn = t + 8;
        if (tn > TLEN - 8) tn = 0;  // safe dummy address for last group
        const float4 xa_n = *(const float4*)(xp + tn);
        const float4 xb_n = *(const float4*)(xp + tn + 4);

        const float xs[8] = {xa.x, xa.y, xa.z, xa.w, xb.x, xb.y, xb.z, xb.w};
        // x contribution is h-independent: precompute off the critical chain.
        float z0[8];
#pragma unroll
        for (int u = 0; u < 8; ++u) z0[u] = fmaf(xs[u], wih, bias);
        float y[8];

#pragma unroll
        for (int u = 0; u < 8; ++u) {
            // Cross-quad h gather (direction-unambiguous DPP, h quad-uniform):
            const float h1 = dpp<0x141>(h);  // row_half_mirror -> h_{jc^1}
            const float h2 = dpp<0x128>(h);  // row_ror:8       -> h_{jc^2}
            const float h3 = dpp<0x140>(h);  // row_mirror      -> h_{jc^3}

            float z = fmaf(wh_0, h,  z0[u]);
            z = fmaf(wh_1, h1, z);
            z = fmaf(wh_2, h2, z);
            z = fmaf(wh_3, h3, z);

            const float v = fmaf(Aact, frcp(1.0f + fexp2(z)), Bact);

            // All four gates of column jc live in this quad: broadcast each.
            const float iv = dpp<0x00>(v);   // quad lane 0: i
            const float fv = dpp<0x55>(v);   // quad lane 1: f
            const float gv = dpp<0xAA>(v);   // quad lane 2: 2L2E*tanh(g)
            const float ov = dpp<0xFF>(v);   // quad lane 3: o

            C = fmaf(fv, C, iv * gv);        // scaled cell update
            const float tc = fmaf(-2.0f, frcp(1.0f + fexp2(C)), 1.0f);
            h = ov * tc;                     // quad-uniform again

            // y_t = sum_jc wlin_jc h_jc + blin; p is quad-uniform, reduce
            // across quads with direction-free DPP.
            float p = wlin * h;
            p += dpp<0x128>(p);   // + p_{jc^2} (ror:8)
            p += dpp<0x141>(p);   // + p_{jc^1} + p_{jc^3} (half_mirror)
            y[u] = p + blin;
        }

        if (r == 0) {
            *(float4*)(op + t)     = make_float4(y[0], y[1], y[2], y[3]);
            *(float4*)(op + t + 4) = make_float4(y[4], y[5], y[6], y[7]);
        }

        xa = xa_n;
        xb = xb_n;
    }
}

extern "C" void kernel_launch(void* const* d_in, const int* in_sizes, int n_in,
                              void* d_out, int out_size, void* d_ws, size_t ws_size,
                              hipStream_t stream) {
    const float* x     = (const float*)d_in[0];
    const float* W_ih  = (const float*)d_in[1];
    const float* W_hh  = (const float*)d_in[2];
    const float* b_ih  = (const float*)d_in[3];
    const float* b_hh  = (const float*)d_in[4];
    const float* W_lin = (const float*)d_in[5];
    const float* b_lin = (const float*)d_in[6];
    float* out = (float*)d_out;

    const int B = in_sizes[0] / TLEN;          // 4096
    const int threads = B * 16;                // 16 lanes per sequence
    const int block = 256;                     // 4 waves/block -> 1 block/CU
    const int grid = threads / block;          // 256 blocks, 1024 waves

    lstm16t_kernel<<<grid, block, 0, stream>>>(x, W_ih, W_hh, b_ih, b_hh,
                                               W_lin, b_lin, out);
}